// Round 2
// baseline (2123.060 us; speedup 1.0000x reference)
//
#include <hip/hip_runtime.h>
#include <hip/hip_bf16.h>
#include <stdint.h>

// BConv2d: out = conv2d(sign(x), sign(w), pad=1) + b
// N=32, Cin=256, H=W=56, Cout=256, K=3. fp32 in/out.
//
// dot(±1,±1) over 256-bit tap = 256 - 2*popcount(xor). OOB taps packed as
// all-zero bits (== all -1); false contribution removed via per-(border,co)
// table adj[bt][co] = bias[co] - sum_invalid(256 - 2*pop(w_tap)).

#define NBATCH 32
#define CIN    256
#define COUT   256
#define HH     56
#define WW     56
#define HW     (HH*WW)          // 3136
#define NPIX   (NBATCH*HW)      // 100352
#define CO_CHUNK 32

#define XP_BYTES ((size_t)NPIX * 8 * 4)        // 3,211,264
#define WP_BYTES ((size_t)COUT * 72 * 4)       // 73,728

// ---- pack x: wave handles 64 channels (2 words) for 64 pixels (lane=pixel)
__global__ __launch_bounds__(256) void pack_x_kernel(
    const float* __restrict__ x, uint32_t* __restrict__ xp)
{
    int lane = threadIdx.x & 63;
    int wv   = threadIdx.x >> 6;               // 0..3 -> channel group
    int pix  = blockIdx.x * 64 + lane;         // 1568 blocks * 64 == NPIX
    int n  = pix / HW;
    int hw = pix - n * HW;
    const float* xb = x + ((size_t)n * CIN + (size_t)wv * 64) * HW + hw;

    uint32_t w0 = 0, w1 = 0;
    #pragma unroll
    for (int j = 0; j < 32; ++j) {
        w0 |= (xb[(size_t)j * HW]        >= 0.0f ? 1u : 0u) << j;
        w1 |= (xb[(size_t)(j + 32) * HW] >= 0.0f ? 1u : 0u) << j;
    }
    *(uint2*)(xp + (size_t)pix * 8 + wv * 2) = make_uint2(w0, w1);
}

// ---- pack w: one block per co; lane = ci; ballot builds packed words
__global__ __launch_bounds__(256) void pack_w_kernel(
    const float* __restrict__ w, const float* __restrict__ bias,
    uint32_t* __restrict__ wp, float* __restrict__ adj)
{
    int co   = blockIdx.x;
    int ci   = threadIdx.x;                    // 0..255
    int lane = ci & 63, wv = ci >> 6;
    const float* wb = w + ((size_t)co * CIN + ci) * 9;

    float v[9];
    #pragma unroll
    for (int t = 0; t < 9; ++t) v[t] = wb[t];

    __shared__ int pops[4][9];
    __shared__ int popv[9];

    #pragma unroll
    for (int t = 0; t < 9; ++t) {
        unsigned long long m = __ballot(v[t] >= 0.0f);
        if (lane == 0) {
            wp[(size_t)co * 72 + t * 8 + 2 * wv]     = (uint32_t)m;
            wp[(size_t)co * 72 + t * 8 + 2 * wv + 1] = (uint32_t)(m >> 32);
            pops[wv][t] = (int)__popcll(m);
        }
    }
    __syncthreads();
    if (ci < 9) popv[ci] = pops[0][ci] + pops[1][ci] + pops[2][ci] + pops[3][ci];
    __syncthreads();
    if (ci < 9) {
        int bt = ci, ht = bt / 3, wt = bt % 3;
        float c = 0.0f;
        #pragma unroll
        for (int t = 0; t < 9; ++t) {
            int dh = t / 3, dw = t % 3;
            bool inv = (ht == 0 && dh == 0) || (ht == 2 && dh == 2) ||
                       (wt == 0 && dw == 0) || (wt == 2 && dw == 2);
            if (inv) c += (float)(CIN - 2 * popv[t]);
        }
        adj[bt * COUT + co] = bias[co] - c;
    }
}

// ---- conv: thread computes 2 adjacent pixels (w0, w0+1) x CO_CHUNK co
__global__ __launch_bounds__(256, 4) void bconv_kernel(
    const uint32_t* __restrict__ xp, const uint32_t* __restrict__ wp,
    const float* __restrict__ adj, float* __restrict__ out)
{
    int q   = blockIdx.x * 256 + threadIdx.x;  // pair index; 196 blocks
    int co0 = blockIdx.y * CO_CHUNK;

    int n   = q / (HW / 2);
    int rem = q - n * (HW / 2);
    int h   = rem / (WW / 2);
    int w0  = (rem - h * (WW / 2)) * 2;

    // 12 tap locations: rows h-1..h+1, cols w0-1..w0+2
    uint32_t xb[3][4][8];
    #pragma unroll
    for (int r = 0; r < 3; ++r) {
        int hh = h + r - 1;
        #pragma unroll
        for (int cc = 0; cc < 4; ++cc) {
            int ww = w0 + cc - 1;
            if ((unsigned)hh < HH && (unsigned)ww < WW) {
                const uint4* src = (const uint4*)(xp + ((size_t)n * HW + hh * WW + ww) * 8);
                uint4 a = src[0], b4 = src[1];
                xb[r][cc][0] = a.x;  xb[r][cc][1] = a.y;
                xb[r][cc][2] = a.z;  xb[r][cc][3] = a.w;
                xb[r][cc][4] = b4.x; xb[r][cc][5] = b4.y;
                xb[r][cc][6] = b4.z; xb[r][cc][7] = b4.w;
            } else {
                #pragma unroll
                for (int j = 0; j < 8; ++j) xb[r][cc][j] = 0;
            }
        }
    }

    int ht  = (h == 0) ? 0 : ((h == HH - 1) ? 2 : 1);
    int wt0 = (w0 == 0) ? 0 : 1;               // pixel0 col is even (<=54)
    int wt1 = (w0 + 1 == WW - 1) ? 2 : 1;      // pixel1 col is odd  (>=1)
    const float* adj0 = adj + (ht * 3 + wt0) * COUT;
    const float* adj1 = adj + (ht * 3 + wt1) * COUT;

    float* outp = out + (size_t)n * COUT * HW + h * WW + w0;

    for (int c = 0; c < CO_CHUNK; ++c) {
        int co = co0 + c;
        const uint32_t* wrow = wp + (size_t)co * 72;   // uniform -> s_loads
        int p0a = 0, p0b = 0, p1a = 0, p1b = 0;
        #pragma unroll
        for (int t = 0; t < 9; ++t) {
            int r = t / 3, d = t % 3;
            #pragma unroll
            for (int j = 0; j < 8; ++j) {
                uint32_t wvv = wrow[t * 8 + j];
                if (j < 4) {
                    p0a += __popc(xb[r][d][j] ^ wvv);
                    p1a += __popc(xb[r][d + 1][j] ^ wvv);
                } else {
                    p0b += __popc(xb[r][d][j] ^ wvv);
                    p1b += __popc(xb[r][d + 1][j] ^ wvv);
                }
            }
        }
        float v0 = (float)(2304 - 2 * (p0a + p0b)) + adj0[co];
        float v1 = (float)(2304 - 2 * (p1a + p1b)) + adj1[co];
        *(float2*)(outp + (size_t)co * HW) = make_float2(v0, v1);
    }
}

extern "C" void kernel_launch(void* const* d_in, const int* in_sizes, int n_in,
                              void* d_out, int out_size, void* d_ws, size_t ws_size,
                              hipStream_t stream) {
    const float* x = (const float*)d_in[0];
    const float* w = (const float*)d_in[1];
    const float* b = (const float*)d_in[2];
    float* out = (float*)d_out;

    uint32_t* xp   = (uint32_t*)d_ws;
    uint32_t* wpck = (uint32_t*)((char*)d_ws + XP_BYTES);
    float*    adjp = (float*)((char*)d_ws + XP_BYTES + WP_BYTES);

    pack_x_kernel<<<NPIX / 64, 256, 0, stream>>>(x, xp);
    pack_w_kernel<<<COUT, 256, 0, stream>>>(w, b, wpck, adjp);

    dim3 grid(NPIX / 2 / 256, COUT / CO_CHUNK);
    bconv_kernel<<<grid, 256, 0, stream>>>(xp, wpck, adjp, out);
}

// Round 3
// 167.752 us; speedup vs baseline: 12.6560x; 12.6560x over previous
//
#include <hip/hip_runtime.h>
#include <hip/hip_bf16.h>
#include <stdint.h>

// BConv2d: out = conv2d(sign(x), sign(w), pad=1) + b
// N=32, Cin=256, H=W=56, Cout=256, K=3. fp32 in/out.
//
// dot(±1,±1) over 256-bit tap = 256 - 2*popcount(xor). OOB taps packed as
// all-zero bits (== all -1); false contribution removed via per-(border,co)
// table adj[bt][co] = bias[co] - sum_invalid(256 - 2*pop(w_tap)).
//
// R2 lesson: __launch_bounds__(256,4) forced VGPR=64 -> xb[] spilled to
// scratch (FETCH 4.3 GB). Use (256,2) so the ~130-reg live set stays in regs.
// R3: vertical pixel pair (h,h+1) per thread -> 12 tap locations, 2x weight
// s_load amortization, and consecutive threads keep consecutive w (coalesced).

#define NBATCH 32
#define CIN    256
#define COUT   256
#define HH     56
#define WW     56
#define HW     (HH*WW)          // 3136
#define NPIX   (NBATCH*HW)      // 100352
#define CO_CHUNK 32

#define XP_BYTES ((size_t)NPIX * 8 * 4)        // 3,211,264
#define WP_BYTES ((size_t)COUT * 72 * 4)       // 73,728

// ---- pack x: wave handles 64 channels (2 words) for 64 pixels (lane=pixel)
__global__ __launch_bounds__(256) void pack_x_kernel(
    const float* __restrict__ x, uint32_t* __restrict__ xp)
{
    int lane = threadIdx.x & 63;
    int wv   = threadIdx.x >> 6;               // 0..3 -> channel group
    int pix  = blockIdx.x * 64 + lane;         // 1568 blocks * 64 == NPIX
    int n  = pix / HW;
    int hw = pix - n * HW;
    const float* xb = x + ((size_t)n * CIN + (size_t)wv * 64) * HW + hw;

    uint32_t w0 = 0, w1 = 0;
    #pragma unroll
    for (int j = 0; j < 32; ++j) {
        w0 |= (xb[(size_t)j * HW]        >= 0.0f ? 1u : 0u) << j;
        w1 |= (xb[(size_t)(j + 32) * HW] >= 0.0f ? 1u : 0u) << j;
    }
    *(uint2*)(xp + (size_t)pix * 8 + wv * 2) = make_uint2(w0, w1);
}

// ---- pack w: one block per co; lane = ci; ballot builds packed words
__global__ __launch_bounds__(256) void pack_w_kernel(
    const float* __restrict__ w, const float* __restrict__ bias,
    uint32_t* __restrict__ wp, float* __restrict__ adj)
{
    int co   = blockIdx.x;
    int ci   = threadIdx.x;                    // 0..255
    int lane = ci & 63, wv = ci >> 6;
    const float* wb = w + ((size_t)co * CIN + ci) * 9;

    float v[9];
    #pragma unroll
    for (int t = 0; t < 9; ++t) v[t] = wb[t];

    __shared__ int pops[4][9];
    __shared__ int popv[9];

    #pragma unroll
    for (int t = 0; t < 9; ++t) {
        unsigned long long m = __ballot(v[t] >= 0.0f);
        if (lane == 0) {
            wp[(size_t)co * 72 + t * 8 + 2 * wv]     = (uint32_t)m;
            wp[(size_t)co * 72 + t * 8 + 2 * wv + 1] = (uint32_t)(m >> 32);
            pops[wv][t] = (int)__popcll(m);
        }
    }
    __syncthreads();
    if (ci < 9) popv[ci] = pops[0][ci] + pops[1][ci] + pops[2][ci] + pops[3][ci];
    __syncthreads();
    if (ci < 9) {
        int bt = ci, ht = bt / 3, wt = bt % 3;
        float c = 0.0f;
        #pragma unroll
        for (int t = 0; t < 9; ++t) {
            int dh = t / 3, dw = t % 3;
            bool inv = (ht == 0 && dh == 0) || (ht == 2 && dh == 2) ||
                       (wt == 0 && dw == 0) || (wt == 2 && dw == 2);
            if (inv) c += (float)(CIN - 2 * popv[t]);
        }
        adj[bt * COUT + co] = bias[co] - c;
    }
}

// ---- conv: thread computes vertical pixel pair (h,w) and (h+1,w)
__global__ __launch_bounds__(256, 2) void bconv_kernel(
    const uint32_t* __restrict__ xp, const uint32_t* __restrict__ wp,
    const float* __restrict__ adj, float* __restrict__ out)
{
    int q   = blockIdx.x * 256 + threadIdx.x;  // pair index; 196 blocks
    int co0 = blockIdx.y * CO_CHUNK;

    int n   = q / (HW / 2);
    int rem = q - n * (HW / 2);                // 0..1567 = 28 row-pairs x 56
    int hp  = rem / WW;
    int w_  = rem - hp * WW;                   // consecutive q -> consecutive w
    int h   = hp * 2;                          // 0,2,...,54

    // 12 tap locations: rows h-1..h+2, cols w-1..w+1
    uint32_t xb[4][3][8];
    #pragma unroll
    for (int r = 0; r < 4; ++r) {
        int hh = h + r - 1;
        #pragma unroll
        for (int cc = 0; cc < 3; ++cc) {
            int ww = w_ + cc - 1;
            if ((unsigned)hh < HH && (unsigned)ww < WW) {
                const uint4* src = (const uint4*)(xp + ((size_t)n * HW + hh * WW + ww) * 8);
                uint4 a = src[0], b4 = src[1];
                xb[r][cc][0] = a.x;  xb[r][cc][1] = a.y;
                xb[r][cc][2] = a.z;  xb[r][cc][3] = a.w;
                xb[r][cc][4] = b4.x; xb[r][cc][5] = b4.y;
                xb[r][cc][6] = b4.z; xb[r][cc][7] = b4.w;
            } else {
                #pragma unroll
                for (int j = 0; j < 8; ++j) xb[r][cc][j] = 0;
            }
        }
    }

    int ht0 = (h == 0) ? 0 : 1;                // pixel0 row: 0..54, never bottom
    int ht1 = (h + 1 == HH - 1) ? 2 : 1;       // pixel1 row: 1..55, never top
    int wt  = (w_ == 0) ? 0 : ((w_ == WW - 1) ? 2 : 1);
    const float* adj0 = adj + (ht0 * 3 + wt) * COUT;
    const float* adj1 = adj + (ht1 * 3 + wt) * COUT;

    float* outp = out + (size_t)n * COUT * HW + h * WW + w_;

    for (int c = 0; c < CO_CHUNK; ++c) {
        int co = co0 + c;
        const uint32_t* wrow = wp + (size_t)co * 72;   // uniform -> s_loads
        int p0a = 0, p0b = 0, p1a = 0, p1b = 0;
        #pragma unroll
        for (int t = 0; t < 9; ++t) {
            int r = t / 3, d = t % 3;
            #pragma unroll
            for (int j = 0; j < 8; ++j) {
                uint32_t wvv = wrow[t * 8 + j];
                if (j < 4) {
                    p0a += __popc(xb[r][d][j] ^ wvv);
                    p1a += __popc(xb[r + 1][d][j] ^ wvv);
                } else {
                    p0b += __popc(xb[r][d][j] ^ wvv);
                    p1b += __popc(xb[r + 1][d][j] ^ wvv);
                }
            }
        }
        float v0 = (float)(2304 - 2 * (p0a + p0b)) + adj0[co];
        float v1 = (float)(2304 - 2 * (p1a + p1b)) + adj1[co];
        outp[(size_t)co * HW]      = v0;
        outp[(size_t)co * HW + WW] = v1;
    }
}

extern "C" void kernel_launch(void* const* d_in, const int* in_sizes, int n_in,
                              void* d_out, int out_size, void* d_ws, size_t ws_size,
                              hipStream_t stream) {
    const float* x = (const float*)d_in[0];
    const float* w = (const float*)d_in[1];
    const float* b = (const float*)d_in[2];
    float* out = (float*)d_out;

    uint32_t* xp   = (uint32_t*)d_ws;
    uint32_t* wpck = (uint32_t*)((char*)d_ws + XP_BYTES);
    float*    adjp = (float*)((char*)d_ws + XP_BYTES + WP_BYTES);

    pack_x_kernel<<<NPIX / 64, 256, 0, stream>>>(x, xp);
    pack_w_kernel<<<COUT, 256, 0, stream>>>(w, b, wpck, adjp);

    dim3 grid(NPIX / 2 / 256, COUT / CO_CHUNK);
    bconv_kernel<<<grid, 256, 0, stream>>>(xp, wpck, adjp, out);
}